// Round 3
// baseline (474.209 us; speedup 1.0000x reference)
//
#include <hip/hip_runtime.h>
#include <stdint.h>

#define N_BANK 200000
#define N_PAD  201600          // 63 chunks * 3200 cols
#define NQ     2048
#define DIMD   128
#define C_IN   112
#define NCHUNK 63
#define CHUNK_COLS 3200
#define STEP_COLS 64           // double-buffered sub-tile (16 KB)
#define NSTEP  50              // CHUNK_COLS / STEP_COLS
#define NCE    126             // NCHUNK * 2 wave-col halves
#define NC3    378             // NCE * 3
#define NBANKBLK 50400         // N_PAD / 4 bank-rows blocks in prep
#define NEMBBLK  1024          // 2048 queries / 2 per block

typedef short v8s __attribute__((ext_vector_type(8)));
typedef float v4f __attribute__((ext_vector_type(4)));

typedef const __attribute__((address_space(1))) uint32_t* gp1_t;
typedef __attribute__((address_space(3))) uint32_t* lp3_t;

__device__ __forceinline__ void async16(const void* g, void* l) {
  __builtin_amdgcn_global_load_lds((gp1_t)g, (lp3_t)l, 16, 0, 0);
}

__device__ __forceinline__ unsigned short f2bf(float f) {
  uint32_t u = __float_as_uint(f);
  u += 0x7fff + ((u >> 16) & 1);   // round-to-nearest-even
  return (unsigned short)(u >> 16);
}

// running top-3 insert: 3 independent VALU ops (all read OLD state)
__device__ __forceinline__ void insert3(float& m1, float& m2, float& m3, float v) {
  m3 = __builtin_amdgcn_fmed3f(m2, m3, v);
  m2 = __builtin_amdgcn_fmed3f(m1, m2, v);
  m1 = fmaxf(m1, v);
}

// ---------------- kernel 1: fused prep = bank L2 norm + patch embedding ----
// blocks [0, 50400): 4 bank rows each (norm -> bf16, 16B-block swizzled rows)
// blocks [50400, 51424): 2 queries each (proj + L2 norm -> bf16, same swizzle)
__global__ void prep_kernel(const float* __restrict__ fm, const float* __restrict__ pw,
                            const float* __restrict__ bank,
                            unsigned short* __restrict__ embB,
                            unsigned short* __restrict__ bankB) {
  int blk = blockIdx.x;
  int tid = threadIdx.x;
  if (blk < NBANKBLK) {
    // ---- bank part: one row per wave ----
    int wv = tid >> 6, lane = tid & 63;
    int r = blk * 4 + wv;
    uint32_t* out = (uint32_t*)bankB;     // packed 2x bf16
    int j = lane >> 2, w = lane & 3;      // 16B block, dword within
    int sdw = ((j ^ (r & 15)) << 2) | w;  // swizzled dword index in row
    if (r < N_BANK) {
      float2 v = ((const float2*)bank)[r * 64 + lane];
      float s = v.x * v.x + v.y * v.y;
#pragma unroll
      for (int off = 32; off; off >>= 1) s += __shfl_xor(s, off);
      float scale = 1.f / fmaxf(sqrtf(s), 1e-12f);
      uint32_t lo = f2bf(v.x * scale);
      uint32_t hi = f2bf(v.y * scale);
      out[r * 64 + sdw] = lo | (hi << 16);
    } else {
      out[r * 64 + sdw] = 0u;
    }
  } else {
    // ---- emb part: 2 queries per block (128 threads each) ----
    __shared__ float x[2][C_IN];
    __shared__ float wsum[4];
    int half = tid >> 7;                 // which query in this block
    int t = tid & 127;                   // output dim 0..127
    int q = (blk - NBANKBLK) * 2 + half; // 0..2047
    int b = q >> 8, p = q & 255;
    if (t < C_IN) x[half][t] = fm[(b * C_IN + t) * 256 + p];
    __syncthreads();
    const float* row = pw + t * C_IN;
    float dot = 0.f;
#pragma unroll
    for (int c = 0; c < C_IN; ++c) dot = fmaf(x[half][c], row[c], dot);
    float s = dot * dot;
#pragma unroll
    for (int off = 32; off; off >>= 1) s += __shfl_xor(s, off);
    int wv = tid >> 6, lane = tid & 63;
    if (lane == 0) wsum[wv] = s;
    __syncthreads();
    float ss = wsum[half * 2] + wsum[half * 2 + 1];
    float scale = 1.f / fmaxf(sqrtf(ss), 1e-12f);
    int j = t >> 3, pos = t & 7;                     // 16B block, elem within
    int sw = j ^ (q & 15);                           // bank-conflict swizzle
    embB[q * DIMD + sw * 8 + pos] = f2bf(dot * scale);
  }
}

// ---------------- kernel 2: fused sims GEMM + running top-3 -----------------
// 1-D grid of 1008 blocks, XCD-grouped decode so all 16 M-tiles of a chunk
// land on one XCD's L2. 256 threads = 4 waves in 2x2 (64 rows x 32 cols/wave
// per step). B double-buffered in LDS (2 x 16 KB), counted vmcnt.
// launch_bounds(256,4): 4 blocks/CU (LDS 128/160 KB, VGPR <=128) -> whole
// grid resident, cross-block TLP covers per-step barrier/vmcnt stalls.
__global__ __launch_bounds__(256, 4)
void sim_top3_kernel(const unsigned short* __restrict__ embB,
                     const unsigned short* __restrict__ bankB,
                     float* __restrict__ partial) {
  // ---- bijective XCD-grouping decode: chunks [7x, 7x+7) -> XCD x ----
  int id = blockIdx.x;
  int chunk, mt;
  if (id < 896) {                      // 8 XCDs * 7 chunks * 16 M-tiles
    int x = id & 7, j = id >> 3;
    chunk = x * 7 + (j >> 4);
    mt = j & 15;
  } else {                             // tail chunks 56..62
    int t2 = id - 896;
    chunk = 56 + (t2 >> 4);
    mt = t2 & 15;
  }
  int q0 = mt * 128;
  int tid = threadIdx.x;
  int wv = tid >> 6, lane = tid & 63;
  int wr = wv >> 1, wc = wv & 1;       // wave row/col in 2x2
  int g = lane >> 4, c0 = lane & 15;   // frag k-group / col-class

  __shared__ __align__(16) unsigned char lds[32768];   // 2 x 16 KB B buffers

  // ---- stage A tile (128 rows x 128 K, bf16, swizzled) through both bufs ----
  {
    const char* gbase = (const char*)embB + q0 * 256;
#pragma unroll
    for (int i = 0; i < 8; ++i) {
      int off = i * 4096 + tid * 16;
      async16(gbase + off, lds + off);
    }
  }
  asm volatile("s_waitcnt vmcnt(0)" ::: "memory");
  __builtin_amdgcn_sched_barrier(0);
  __builtin_amdgcn_s_barrier();

  // ---- hoist A fragments to registers, persistent for all steps ----
  v8s a[4][4];
#pragma unroll
  for (int fm = 0; fm < 4; ++fm)
#pragma unroll
    for (int k = 0; k < 4; ++k) {
      int row = wr * 64 + fm * 16 + c0;
      a[fm][k] = *(const v8s*)(lds + row * 256 + (((k * 4 + g) ^ c0) << 4));
    }
  // all waves must finish reading A before B staging overwrites the buffers
  asm volatile("s_waitcnt lgkmcnt(0)" ::: "memory");
  __builtin_amdgcn_sched_barrier(0);
  __builtin_amdgcn_s_barrier();

  float m1[16], m2[16], m3[16];
#pragma unroll
  for (int t = 0; t < 16; ++t) { m1[t] = -1e30f; m2[t] = -1e30f; m3[t] = -1e30f; }

  const char* bbase = (const char*)bankB + (size_t)chunk * CHUNK_COLS * 256;

  // ---- prologue: stage step 0 into buf0 (4 async16/thread = 16 KB/block) ----
#pragma unroll
  for (int i = 0; i < 4; ++i) {
    int off = i * 4096 + tid * 16;
    async16(bbase + off, lds + off);
  }

  for (int s = 0; s < NSTEP; ++s) {
    if (s + 1 < NSTEP) {
      // issue next-step stage FIRST, then wait only for the current buffer
      const char* gsrc = bbase + (size_t)(s + 1) * (STEP_COLS * 256);
      unsigned char* ldst = lds + ((s + 1) & 1) * 16384;
#pragma unroll
      for (int i = 0; i < 4; ++i) {
        int off = i * 4096 + tid * 16;
        async16(gsrc + off, ldst + off);
      }
      asm volatile("s_waitcnt vmcnt(4)" ::: "memory");  // prefetch stays in flight
    } else {
      asm volatile("s_waitcnt vmcnt(0)" ::: "memory");  // epilogue: drain last buffer
    }
    __builtin_amdgcn_sched_barrier(0);
    __builtin_amdgcn_s_barrier();                       // buf[cur] ready across waves

    const unsigned char* bp = lds + (s & 1) * 16384;
#pragma unroll
    for (int fn = 0; fn < 2; ++fn) {
      v8s bf[4];
      int col = wc * 32 + fn * 16 + c0;
#pragma unroll
      for (int k = 0; k < 4; ++k)
        bf[k] = *(const v8s*)(bp + col * 256 + (((k * 4 + g) ^ c0) << 4));
#pragma unroll
      for (int fm = 0; fm < 4; ++fm) {
        v4f acc = {0.f, 0.f, 0.f, 0.f};
#pragma unroll
        for (int k = 0; k < 4; ++k)
          acc = __builtin_amdgcn_mfma_f32_16x16x32_bf16(a[fm][k], bf[k], acc, 0, 0, 0);
#pragma unroll
        for (int j = 0; j < 4; ++j)        // C/D: row=g*4+j, col=c0 (within frag)
          insert3(m1[fm * 4 + j], m2[fm * 4 + j], m3[fm * 4 + j], acc[j]);
      }
    }
    // all waves done reading buf[cur] before next iteration overwrites it
    __builtin_amdgcn_s_barrier();
  }

  // ---- merge top-3 across the 16 col-class lanes (butterfly) ----
#pragma unroll
  for (int mask = 1; mask < 16; mask <<= 1) {
#pragma unroll
    for (int t = 0; t < 16; ++t) {
      float b1 = __shfl_xor(m1[t], mask);
      float b2 = __shfl_xor(m2[t], mask);
      float b3 = __shfl_xor(m3[t], mask);
      insert3(m1[t], m2[t], m3[t], b1);
      insert3(m1[t], m2[t], m3[t], b2);
      insert3(m1[t], m2[t], m3[t], b3);
    }
  }

  if (c0 == 0) {
    int ce = chunk * 2 + wc;               // per wave-col half partials
#pragma unroll
    for (int t = 0; t < 16; ++t) {
      int q = q0 + wr * 64 + (t >> 2) * 16 + g * 4 + (t & 3);
      float* dst = partial + (size_t)q * NC3 + ce * 3;   // query-major
      dst[0] = m1[t];
      dst[1] = m2[t];
      dst[2] = m3[t];
    }
  }
}

// ---------------- kernel 3: fused final = per-query merge + top-8 mean ------
// one block per image; thread q' owns query b*256+q' (scan 378 partials,
// top-3 -> distance), then in-block top-8 tree over the 256 distances.
__global__ void final_kernel(const float* __restrict__ partial, float* __restrict__ out) {
  int b = blockIdx.x;            // image
  int tid = threadIdx.x;         // patch 0..255
  int q = b * 256 + tid;
  const float* src = partial + (size_t)q * NC3;
  float m1 = -1e30f, m2 = -1e30f, m3 = -1e30f;
  for (int c = 0; c < NC3; ++c) insert3(m1, m2, m3, src[c]);
  float d1 = sqrtf(fmaxf(2.f - 2.f * m1, 0.f));
  float d2 = sqrtf(fmaxf(2.f - 2.f * m2, 0.f));
  float d3 = sqrtf(fmaxf(2.f - 2.f * m3, 0.f));
  float d = (d1 + d2 + d3) * (1.f / 3.f);

  __shared__ float vals[256];
  __shared__ float rv[256];
  __shared__ int ri[256];
  vals[tid] = d;
  __syncthreads();
  float sum = 0.f;
  for (int iter = 0; iter < 8; ++iter) {   // k = ceil(256*0.03) = 8
    rv[tid] = vals[tid]; ri[tid] = tid;
    __syncthreads();
    for (int s = 128; s > 0; s >>= 1) {
      if (tid < s && rv[tid + s] > rv[tid]) { rv[tid] = rv[tid + s]; ri[tid] = ri[tid + s]; }
      __syncthreads();
    }
    sum += rv[0];
    if (tid == 0) vals[ri[0]] = -1e30f;
    __syncthreads();
  }
  if (tid == 0) out[b] = sum * (1.f / 8.f);
}

extern "C" void kernel_launch(void* const* d_in, const int* in_sizes, int n_in,
                              void* d_out, int out_size, void* d_ws, size_t ws_size,
                              hipStream_t stream) {
  const float* fm   = (const float*)d_in[0];   // [8,112,16,16]
  const float* pw   = (const float*)d_in[1];   // [128,112]
  const float* bank = (const float*)d_in[2];   // [200000,128]
  float* out = (float*)d_out;                  // [8]

  char* ws = (char*)d_ws;
  unsigned short* bankB = (unsigned short*)ws;                       // 51,609,600 B
  unsigned short* embB  = (unsigned short*)(ws + 51609600);          //    524,288 B
  float* partial        = (float*)(ws + 51609600 + 524288);          //  3,096,576 B

  prep_kernel<<<NBANKBLK + NEMBBLK, 256, 0, stream>>>(fm, pw, bank, embB, bankB);
  sim_top3_kernel<<<16 * NCHUNK, 256, 0, stream>>>(embB, bankB, partial);
  final_kernel<<<8, 256, 0, stream>>>(partial, out);
}

// Round 4
// 368.680 us; speedup vs baseline: 1.2862x; 1.2862x over previous
//
#include <hip/hip_runtime.h>
#include <stdint.h>

#define N_BANK 200000
#define N_PAD  201600          // 3150 steps * 64 cols
#define NQ     2048
#define DIMD   128
#define C_IN   112
#define NCB    48              // column blocks (16KB-step granularity, 65 or 66 steps)
#define NSTEPS_TOT 3150        // N_PAD / 64
#define NCE    96              // NCB * 2 wave-col halves
#define NC3    288             // NCE * 3
#define NBANKBLK 50400         // N_PAD / 4 bank-row blocks in prep
#define NEMBBLK  1024          // 2048 queries / 2 per block

typedef short v8s __attribute__((ext_vector_type(8)));
typedef float v4f __attribute__((ext_vector_type(4)));

typedef const __attribute__((address_space(1))) uint32_t* gp1_t;
typedef __attribute__((address_space(3))) uint32_t* lp3_t;

__device__ __forceinline__ void async16(const void* g, void* l) {
  __builtin_amdgcn_global_load_lds((gp1_t)g, (lp3_t)l, 16, 0, 0);
}

__device__ __forceinline__ unsigned short f2bf(float f) {
  uint32_t u = __float_as_uint(f);
  u += 0x7fff + ((u >> 16) & 1);   // round-to-nearest-even
  return (unsigned short)(u >> 16);
}

// running top-3 insert: 3 independent VALU ops (all read OLD state)
__device__ __forceinline__ void insert3(float& m1, float& m2, float& m3, float v) {
  m3 = __builtin_amdgcn_fmed3f(m2, m3, v);
  m2 = __builtin_amdgcn_fmed3f(m1, m2, v);
  m1 = fmaxf(m1, v);
}

// ---------------- kernel 1: fused prep = bank L2 norm + patch embedding ----
// blocks [0, 50400): 4 bank rows each (norm -> bf16, 16B-block swizzled rows)
// blocks [50400, 51424): 2 queries each (proj + L2 norm -> bf16, same swizzle)
__global__ void prep_kernel(const float* __restrict__ fm, const float* __restrict__ pw,
                            const float* __restrict__ bank,
                            unsigned short* __restrict__ embB,
                            unsigned short* __restrict__ bankB) {
  int blk = blockIdx.x;
  int tid = threadIdx.x;
  if (blk < NBANKBLK) {
    // ---- bank part: one row per wave ----
    int wv = tid >> 6, lane = tid & 63;
    int r = blk * 4 + wv;
    uint32_t* out = (uint32_t*)bankB;     // packed 2x bf16
    int j = lane >> 2, w = lane & 3;      // 16B block, dword within
    int sdw = ((j ^ (r & 15)) << 2) | w;  // swizzled dword index in row
    if (r < N_BANK) {
      float2 v = ((const float2*)bank)[r * 64 + lane];
      float s = v.x * v.x + v.y * v.y;
#pragma unroll
      for (int off = 32; off; off >>= 1) s += __shfl_xor(s, off);
      float scale = 1.f / fmaxf(sqrtf(s), 1e-12f);
      uint32_t lo = f2bf(v.x * scale);
      uint32_t hi = f2bf(v.y * scale);
      out[r * 64 + sdw] = lo | (hi << 16);
    } else {
      out[r * 64 + sdw] = 0u;
    }
  } else {
    // ---- emb part: 2 queries per block (128 threads each) ----
    __shared__ float x[2][C_IN];
    __shared__ float wsum[4];
    int half = tid >> 7;                 // which query in this block
    int t = tid & 127;                   // output dim 0..127
    int q = (blk - NBANKBLK) * 2 + half; // 0..2047
    int b = q >> 8, p = q & 255;
    if (t < C_IN) x[half][t] = fm[(b * C_IN + t) * 256 + p];
    __syncthreads();
    const float* row = pw + t * C_IN;
    float dot = 0.f;
#pragma unroll
    for (int c = 0; c < C_IN; ++c) dot = fmaf(x[half][c], row[c], dot);
    float s = dot * dot;
#pragma unroll
    for (int off = 32; off; off >>= 1) s += __shfl_xor(s, off);
    int wv = tid >> 6, lane = tid & 63;
    if (lane == 0) wsum[wv] = s;
    __syncthreads();
    float ss = wsum[half * 2] + wsum[half * 2 + 1];
    float scale = 1.f / fmaxf(sqrtf(ss), 1e-12f);
    int j = t >> 3, pos = t & 7;                     // 16B block, elem within
    int sw = j ^ (q & 15);                           // bank-conflict swizzle
    embB[q * DIMD + sw * 8 + pos] = f2bf(dot * scale);
  }
}

// ---------------- kernel 2: fused sims GEMM + running top-3 -----------------
// Grid 768 = 3 blocks/CU * 256 CUs, one perfectly-packed round.
// 48 column-blocks (65 or 66 64-col steps each) x 16 M-tiles; 48 = 8 XCD * 6
// so each XCD owns a contiguous column range (L2 locality).
// 256 threads = 4 waves in 2x2 (64 rows x 32 cols/wave per step).
// B triple-buffered in LDS (3 x 16 KB = 48 KB -> exactly 3 blocks/CU);
// per step: wait vmcnt(4) -> barrier -> issue step s+2 -> compute step s.
// One barrier per step; prefetch 2 steps deep; never drains vmcnt mid-loop.
// launch_bounds(256,3): unified reg cap ~170 >= the ~148 this kernel needs
// (cap 128 at min-waves=4 caused catastrophic spills: 135 MB scratch writes).
__global__ __launch_bounds__(256, 3)
void sim_top3_kernel(const unsigned short* __restrict__ embB,
                     const unsigned short* __restrict__ bankB,
                     float* __restrict__ partial) {
  int id = blockIdx.x;                 // 0..767
  int x = id & 7, j = id >> 3;         // XCD, 0..95
  int cb = x * 6 + (j >> 4);           // column block 0..47
  int mt = j & 15;                     // M tile
  int start = 65 * cb + (cb < 30 ? cb : 30);   // first 64-col step
  int nsteps = (cb < 30) ? 66 : 65;
  int q0 = mt * 128;
  int tid = threadIdx.x;
  int wv = tid >> 6, lane = tid & 63;
  int wr = wv >> 1, wc = wv & 1;       // wave row/col in 2x2
  int g = lane >> 4, c0 = lane & 15;   // frag k-group / col-class

  __shared__ __align__(16) unsigned char lds[49152];   // 3 x 16 KB B buffers

  // ---- stage A tile (128 rows x 128 K, bf16, swizzled) into lds[0..32K) ----
  {
    const char* gbase = (const char*)embB + q0 * 256;
#pragma unroll
    for (int i = 0; i < 8; ++i) {
      int off = i * 4096 + tid * 16;
      async16(gbase + off, lds + off);
    }
  }
  asm volatile("s_waitcnt vmcnt(0)" ::: "memory");
  __builtin_amdgcn_sched_barrier(0);
  __builtin_amdgcn_s_barrier();

  // ---- hoist A fragments to registers, persistent for all steps ----
  v8s a[4][4];
#pragma unroll
  for (int fm = 0; fm < 4; ++fm)
#pragma unroll
    for (int k = 0; k < 4; ++k) {
      int row = wr * 64 + fm * 16 + c0;
      a[fm][k] = *(const v8s*)(lds + row * 256 + (((k * 4 + g) ^ c0) << 4));
    }
  // all waves must finish reading A before B staging overwrites the buffers
  asm volatile("s_waitcnt lgkmcnt(0)" ::: "memory");
  __builtin_amdgcn_sched_barrier(0);
  __builtin_amdgcn_s_barrier();

  float m1[16], m2[16], m3[16];
#pragma unroll
  for (int t = 0; t < 16; ++t) { m1[t] = -1e30f; m2[t] = -1e30f; m3[t] = -1e30f; }

  const char* bbase = (const char*)bankB + (size_t)start * 16384;  // 64 cols * 256 B

  unsigned char* b0 = lds;             // holds step s
  unsigned char* b1 = lds + 16384;     // holds step s+1
  unsigned char* b2 = lds + 32768;     // staging target for step s+2

  // ---- prologue: stage steps 0 and 1 (nsteps >= 65, always valid) ----
#pragma unroll
  for (int i = 0; i < 4; ++i) {
    int off = i * 4096 + tid * 16;
    async16(bbase + off, b0 + off);
  }
#pragma unroll
  for (int i = 0; i < 4; ++i) {
    int off = i * 4096 + tid * 16;
    async16(bbase + 16384 + off, b1 + off);
  }

  for (int s = 0; s < nsteps; ++s) {
    // retire step-s loads (oldest 4); keep step-s+1 loads in flight
    if (s + 1 < nsteps) {
      asm volatile("s_waitcnt vmcnt(4)" ::: "memory");
    } else {
      asm volatile("s_waitcnt vmcnt(0)" ::: "memory");
    }
    __builtin_amdgcn_sched_barrier(0);
    __builtin_amdgcn_s_barrier();      // buf s ready everywhere; buf s+2 free
    __builtin_amdgcn_sched_barrier(0);

    if (s + 2 < nsteps) {              // issue step s+2 into b2 (read at s-1)
      const char* gsrc = bbase + (size_t)(s + 2) * 16384;
#pragma unroll
      for (int i = 0; i < 4; ++i) {
        int off = i * 4096 + tid * 16;
        async16(gsrc + off, b2 + off);
      }
    }

    const unsigned char* bp = b0;
#pragma unroll
    for (int fn = 0; fn < 2; ++fn) {
      v8s bf[4];
      int col = wc * 32 + fn * 16 + c0;
#pragma unroll
      for (int k = 0; k < 4; ++k)
        bf[k] = *(const v8s*)(bp + col * 256 + (((k * 4 + g) ^ c0) << 4));
      __builtin_amdgcn_s_setprio(1);
#pragma unroll
      for (int fm = 0; fm < 4; ++fm) {
        v4f acc = {0.f, 0.f, 0.f, 0.f};
#pragma unroll
        for (int k = 0; k < 4; ++k)
          acc = __builtin_amdgcn_mfma_f32_16x16x32_bf16(a[fm][k], bf[k], acc, 0, 0, 0);
#pragma unroll
        for (int j2 = 0; j2 < 4; ++j2)   // C/D: row=g*4+j2, col=c0 (within frag)
          insert3(m1[fm * 4 + j2], m2[fm * 4 + j2], m3[fm * 4 + j2], acc[j2]);
      }
      __builtin_amdgcn_s_setprio(0);
    }

    // rotate buffers: s+1 becomes current, s+2 staging becomes next, s freed
    unsigned char* t0 = b0; b0 = b1; b1 = b2; b2 = t0;
  }

  // ---- merge top-3 across the 16 col-class lanes (butterfly) ----
#pragma unroll
  for (int mask = 1; mask < 16; mask <<= 1) {
#pragma unroll
    for (int t = 0; t < 16; ++t) {
      float v1 = __shfl_xor(m1[t], mask);
      float v2 = __shfl_xor(m2[t], mask);
      float v3 = __shfl_xor(m3[t], mask);
      insert3(m1[t], m2[t], m3[t], v1);
      insert3(m1[t], m2[t], m3[t], v2);
      insert3(m1[t], m2[t], m3[t], v3);
    }
  }

  if (c0 == 0) {
    int ce = cb * 2 + wc;                // per wave-col half partials, 0..95
#pragma unroll
    for (int t = 0; t < 16; ++t) {
      int q = q0 + wr * 64 + (t >> 2) * 16 + g * 4 + (t & 3);
      float* dst = partial + (size_t)q * NC3 + ce * 3;   // query-major
      dst[0] = m1[t];
      dst[1] = m2[t];
      dst[2] = m3[t];
    }
  }
}

// ---------------- kernel 3: fused final = per-query merge + top-8 mean ------
// one block per image; thread q' owns query b*256+q' (scan 288 partials,
// top-3 -> distance), then in-block top-8 tree over the 256 distances.
__global__ void final_kernel(const float* __restrict__ partial, float* __restrict__ out) {
  int b = blockIdx.x;            // image
  int tid = threadIdx.x;         // patch 0..255
  int q = b * 256 + tid;
  const float* src = partial + (size_t)q * NC3;
  float m1 = -1e30f, m2 = -1e30f, m3 = -1e30f;
  for (int c = 0; c < NC3; ++c) insert3(m1, m2, m3, src[c]);
  float d1 = sqrtf(fmaxf(2.f - 2.f * m1, 0.f));
  float d2 = sqrtf(fmaxf(2.f - 2.f * m2, 0.f));
  float d3 = sqrtf(fmaxf(2.f - 2.f * m3, 0.f));
  float d = (d1 + d2 + d3) * (1.f / 3.f);

  __shared__ float vals[256];
  __shared__ float rv[256];
  __shared__ int ri[256];
  vals[tid] = d;
  __syncthreads();
  float sum = 0.f;
  for (int iter = 0; iter < 8; ++iter) {   // k = ceil(256*0.03) = 8
    rv[tid] = vals[tid]; ri[tid] = tid;
    __syncthreads();
    for (int s = 128; s > 0; s >>= 1) {
      if (tid < s && rv[tid + s] > rv[tid]) { rv[tid] = rv[tid + s]; ri[tid] = ri[tid + s]; }
      __syncthreads();
    }
    sum += rv[0];
    if (tid == 0) vals[ri[0]] = -1e30f;
    __syncthreads();
  }
  if (tid == 0) out[b] = sum * (1.f / 8.f);
}

extern "C" void kernel_launch(void* const* d_in, const int* in_sizes, int n_in,
                              void* d_out, int out_size, void* d_ws, size_t ws_size,
                              hipStream_t stream) {
  const float* fm   = (const float*)d_in[0];   // [8,112,16,16]
  const float* pw   = (const float*)d_in[1];   // [128,112]
  const float* bank = (const float*)d_in[2];   // [200000,128]
  float* out = (float*)d_out;                  // [8]

  char* ws = (char*)d_ws;
  unsigned short* bankB = (unsigned short*)ws;                       // 51,609,600 B
  unsigned short* embB  = (unsigned short*)(ws + 51609600);          //    524,288 B
  float* partial        = (float*)(ws + 51609600 + 524288);          //  2,359,296 B

  prep_kernel<<<NBANKBLK + NEMBBLK, 256, 0, stream>>>(fm, pw, bank, embB, bankB);
  sim_top3_kernel<<<768, 256, 0, stream>>>(embB, bankB, partial);
  final_kernel<<<8, 256, 0, stream>>>(partial, out);
}

// Round 5
// 301.803 us; speedup vs baseline: 1.5713x; 1.2216x over previous
//
#include <hip/hip_runtime.h>
#include <stdint.h>

#define N_BANK 200000
#define N_PAD  201600          // 3150 steps * 64 cols
#define NQ     2048
#define DIMD   128
#define C_IN   112
#define NCB    48              // column blocks (65 or 66 64-col steps each)
#define NCE    96              // NCB * 2 wave-col halves
#define NC3    288             // NCE * 3
#define PREP_BANK_BLK 2048     // grid-stride bank-norm blocks
#define PREP_EMB_BLK  1024     // 2048 queries / 2 per block

typedef short v8s __attribute__((ext_vector_type(8)));
typedef float v4f __attribute__((ext_vector_type(4)));

typedef const __attribute__((address_space(1))) uint32_t* gp1_t;
typedef __attribute__((address_space(3))) uint32_t* lp3_t;

__device__ __forceinline__ void async16(const void* g, void* l) {
  __builtin_amdgcn_global_load_lds((gp1_t)g, (lp3_t)l, 16, 0, 0);
}

__device__ __forceinline__ unsigned short f2bf(float f) {
  uint32_t u = __float_as_uint(f);
  u += 0x7fff + ((u >> 16) & 1);   // round-to-nearest-even
  return (unsigned short)(u >> 16);
}

// running top-3 insert: 3 independent VALU ops (all read OLD state)
__device__ __forceinline__ void insert3(float& m1, float& m2, float& m3, float v) {
  m3 = __builtin_amdgcn_fmed3f(m2, m3, v);
  m2 = __builtin_amdgcn_fmed3f(m1, m2, v);
  m1 = fmaxf(m1, v);
}

// ---------------- kernel 1: fused prep = bank L2 norm + patch embedding ----
// blocks [0, 2048): grid-stride over bank rows (4 rows/wave-iter, ~25 iters)
//   -- BW-bound, not block-dispatch-bound (old version: 50400 tiny blocks
//      = 201 sequential block-rounds/CU ~= 120+ us of pure dispatch).
// blocks [2048, 3072): 2 queries each (proj + L2 norm -> bf16, same swizzle)
__global__ void prep_kernel(const float* __restrict__ fm, const float* __restrict__ pw,
                            const float* __restrict__ bank,
                            unsigned short* __restrict__ embB,
                            unsigned short* __restrict__ bankB) {
  int blk = blockIdx.x;
  int tid = threadIdx.x;
  if (blk < PREP_BANK_BLK) {
    // ---- bank part: one row per wave per iteration ----
    int wv = tid >> 6, lane = tid & 63;
    uint32_t* out = (uint32_t*)bankB;     // packed 2x bf16
    int j = lane >> 2, w = lane & 3;      // 16B block, dword within
    for (int r = blk * 4 + wv; r < N_PAD; r += PREP_BANK_BLK * 4) {
      int sdw = ((j ^ (r & 15)) << 2) | w;  // swizzled dword index in row
      if (r < N_BANK) {
        float2 v = ((const float2*)bank)[r * 64 + lane];
        float s = v.x * v.x + v.y * v.y;
#pragma unroll
        for (int off = 32; off; off >>= 1) s += __shfl_xor(s, off);
        float scale = 1.f / fmaxf(sqrtf(s), 1e-12f);
        uint32_t lo = f2bf(v.x * scale);
        uint32_t hi = f2bf(v.y * scale);
        out[r * 64 + sdw] = lo | (hi << 16);
      } else {
        out[r * 64 + sdw] = 0u;
      }
    }
  } else {
    // ---- emb part: 2 queries per block (128 threads each) ----
    __shared__ float x[2][C_IN];
    __shared__ float wsum[4];
    int half = tid >> 7;                 // which query in this block
    int t = tid & 127;                   // output dim 0..127
    int q = (blk - PREP_BANK_BLK) * 2 + half; // 0..2047
    int b = q >> 8, p = q & 255;
    if (t < C_IN) x[half][t] = fm[(b * C_IN + t) * 256 + p];
    __syncthreads();
    const float* row = pw + t * C_IN;
    float dot = 0.f;
#pragma unroll
    for (int c = 0; c < C_IN; ++c) dot = fmaf(x[half][c], row[c], dot);
    float s = dot * dot;
#pragma unroll
    for (int off = 32; off; off >>= 1) s += __shfl_xor(s, off);
    int wv = tid >> 6, lane = tid & 63;
    if (lane == 0) wsum[wv] = s;
    __syncthreads();
    float ss = wsum[half * 2] + wsum[half * 2 + 1];
    float scale = 1.f / fmaxf(sqrtf(ss), 1e-12f);
    int j = t >> 3, pos = t & 7;                     // 16B block, elem within
    int sw = j ^ (q & 15);                           // bank-conflict swizzle
    embB[q * DIMD + sw * 8 + pos] = f2bf(dot * scale);
  }
}

// ---------------- kernel 2: fused sims GEMM + running top-3 -----------------
// EXACT round-2 pipeline body (proven 133 us / 0 phantom traffic):
// double-buffered B (2 x 16 KB), issue-next THEN vmcnt(4), 2 barriers/step,
// compile-time (s&1) LDS addressing, no pointer rotation, no setprio.
// Changes vs round 2: grid 768 = 48 column-blocks x 16 M-tiles (65/66 steps
// each, XCD-grouped: 6 cbs per XCD) packing exactly 3 blocks/CU, and
// launch_bounds(256,3) (cap ~170 regs >= ~148 needed; cap 128 spilled).
__global__ __launch_bounds__(256, 3)
void sim_top3_kernel(const unsigned short* __restrict__ embB,
                     const unsigned short* __restrict__ bankB,
                     float* __restrict__ partial) {
  int id = blockIdx.x;                 // 0..767
  int x = id & 7, j = id >> 3;         // XCD, 0..95
  int cb = x * 6 + (j >> 4);           // column block 0..47
  int mt = j & 15;                     // M tile
  int start = 65 * cb + (cb < 30 ? cb : 30);   // first 64-col step
  int nsteps = (cb < 30) ? 66 : 65;
  int q0 = mt * 128;
  int tid = threadIdx.x;
  int wv = tid >> 6, lane = tid & 63;
  int wr = wv >> 1, wc = wv & 1;       // wave row/col in 2x2
  int g = lane >> 4, c0 = lane & 15;   // frag k-group / col-class

  __shared__ __align__(16) unsigned char lds[32768];   // 2 x 16 KB B buffers

  // ---- stage A tile (128 rows x 128 K, bf16, swizzled) through both bufs ----
  {
    const char* gbase = (const char*)embB + q0 * 256;
#pragma unroll
    for (int i = 0; i < 8; ++i) {
      int off = i * 4096 + tid * 16;
      async16(gbase + off, lds + off);
    }
  }
  asm volatile("s_waitcnt vmcnt(0)" ::: "memory");
  __builtin_amdgcn_sched_barrier(0);
  __builtin_amdgcn_s_barrier();

  // ---- hoist A fragments to registers, persistent for all steps ----
  v8s a[4][4];
#pragma unroll
  for (int fm = 0; fm < 4; ++fm)
#pragma unroll
    for (int k = 0; k < 4; ++k) {
      int row = wr * 64 + fm * 16 + c0;
      a[fm][k] = *(const v8s*)(lds + row * 256 + (((k * 4 + g) ^ c0) << 4));
    }
  // all waves must finish reading A before B staging overwrites the buffers
  asm volatile("s_waitcnt lgkmcnt(0)" ::: "memory");
  __builtin_amdgcn_sched_barrier(0);
  __builtin_amdgcn_s_barrier();

  float m1[16], m2[16], m3[16];
#pragma unroll
  for (int t = 0; t < 16; ++t) { m1[t] = -1e30f; m2[t] = -1e30f; m3[t] = -1e30f; }

  const char* bbase = (const char*)bankB + (size_t)start * 16384;  // 64 cols * 256 B

  // ---- prologue: stage step 0 into buf0 (4 async16/thread = 16 KB/block) ----
#pragma unroll
  for (int i = 0; i < 4; ++i) {
    int off = i * 4096 + tid * 16;
    async16(bbase + off, lds + off);
  }

  for (int s = 0; s < nsteps; ++s) {
    if (s + 1 < nsteps) {
      // issue next-step stage FIRST, then wait only for the current buffer
      const char* gsrc = bbase + (size_t)(s + 1) * 16384;
      unsigned char* ldst = lds + ((s + 1) & 1) * 16384;
#pragma unroll
      for (int i = 0; i < 4; ++i) {
        int off = i * 4096 + tid * 16;
        async16(gsrc + off, ldst + off);
      }
      asm volatile("s_waitcnt vmcnt(4)" ::: "memory");  // prefetch stays in flight
    } else {
      asm volatile("s_waitcnt vmcnt(0)" ::: "memory");  // epilogue: drain last buffer
    }
    __builtin_amdgcn_sched_barrier(0);
    __builtin_amdgcn_s_barrier();                       // buf[cur] ready across waves

    const unsigned char* bp = lds + (s & 1) * 16384;
#pragma unroll
    for (int fn = 0; fn < 2; ++fn) {
      v8s bf[4];
      int col = wc * 32 + fn * 16 + c0;
#pragma unroll
      for (int k = 0; k < 4; ++k)
        bf[k] = *(const v8s*)(bp + col * 256 + (((k * 4 + g) ^ c0) << 4));
#pragma unroll
      for (int fm = 0; fm < 4; ++fm) {
        v4f acc = {0.f, 0.f, 0.f, 0.f};
#pragma unroll
        for (int k = 0; k < 4; ++k)
          acc = __builtin_amdgcn_mfma_f32_16x16x32_bf16(a[fm][k], bf[k], acc, 0, 0, 0);
#pragma unroll
        for (int j2 = 0; j2 < 4; ++j2)     // C/D: row=g*4+j2, col=c0 (within frag)
          insert3(m1[fm * 4 + j2], m2[fm * 4 + j2], m3[fm * 4 + j2], acc[j2]);
      }
    }
    // all waves done reading buf[cur] before next iteration overwrites it
    __builtin_amdgcn_s_barrier();
  }

  // ---- merge top-3 across the 16 col-class lanes (butterfly) ----
#pragma unroll
  for (int mask = 1; mask < 16; mask <<= 1) {
#pragma unroll
    for (int t = 0; t < 16; ++t) {
      float v1 = __shfl_xor(m1[t], mask);
      float v2 = __shfl_xor(m2[t], mask);
      float v3 = __shfl_xor(m3[t], mask);
      insert3(m1[t], m2[t], m3[t], v1);
      insert3(m1[t], m2[t], m3[t], v2);
      insert3(m1[t], m2[t], m3[t], v3);
    }
  }

  if (c0 == 0) {
    int ce = cb * 2 + wc;                // per wave-col half partials, 0..95
#pragma unroll
    for (int t = 0; t < 16; ++t) {
      int q = q0 + wr * 64 + (t >> 2) * 16 + g * 4 + (t & 3);
      float* dst = partial + (size_t)q * NC3 + ce * 3;   // query-major
      dst[0] = m1[t];
      dst[1] = m2[t];
      dst[2] = m3[t];
    }
  }
}

// ---------------- kernel 3: fused final = per-query merge + top-8 mean ------
// one block per image; thread q' owns query b*256+q' (scan 288 partials,
// top-3 -> distance), then in-block top-8 tree over the 256 distances.
__global__ void final_kernel(const float* __restrict__ partial, float* __restrict__ out) {
  int b = blockIdx.x;            // image
  int tid = threadIdx.x;         // patch 0..255
  int q = b * 256 + tid;
  const float* src = partial + (size_t)q * NC3;
  float m1 = -1e30f, m2 = -1e30f, m3 = -1e30f;
  for (int c = 0; c < NC3; ++c) insert3(m1, m2, m3, src[c]);
  float d1 = sqrtf(fmaxf(2.f - 2.f * m1, 0.f));
  float d2 = sqrtf(fmaxf(2.f - 2.f * m2, 0.f));
  float d3 = sqrtf(fmaxf(2.f - 2.f * m3, 0.f));
  float d = (d1 + d2 + d3) * (1.f / 3.f);

  __shared__ float vals[256];
  __shared__ float rv[256];
  __shared__ int ri[256];
  vals[tid] = d;
  __syncthreads();
  float sum = 0.f;
  for (int iter = 0; iter < 8; ++iter) {   // k = ceil(256*0.03) = 8
    rv[tid] = vals[tid]; ri[tid] = tid;
    __syncthreads();
    for (int s = 128; s > 0; s >>= 1) {
      if (tid < s && rv[tid + s] > rv[tid]) { rv[tid] = rv[tid + s]; ri[tid] = ri[tid + s]; }
      __syncthreads();
    }
    sum += rv[0];
    if (tid == 0) vals[ri[0]] = -1e30f;
    __syncthreads();
  }
  if (tid == 0) out[b] = sum * (1.f / 8.f);
}

extern "C" void kernel_launch(void* const* d_in, const int* in_sizes, int n_in,
                              void* d_out, int out_size, void* d_ws, size_t ws_size,
                              hipStream_t stream) {
  const float* fm   = (const float*)d_in[0];   // [8,112,16,16]
  const float* pw   = (const float*)d_in[1];   // [128,112]
  const float* bank = (const float*)d_in[2];   // [200000,128]
  float* out = (float*)d_out;                  // [8]

  char* ws = (char*)d_ws;
  unsigned short* bankB = (unsigned short*)ws;                       // 51,609,600 B
  unsigned short* embB  = (unsigned short*)(ws + 51609600);          //    524,288 B
  float* partial        = (float*)(ws + 51609600 + 524288);          //  2,359,296 B

  prep_kernel<<<PREP_BANK_BLK + PREP_EMB_BLK, 256, 0, stream>>>(fm, pw, bank, embB, bankB);
  sim_top3_kernel<<<768, 256, 0, stream>>>(embB, bankB, partial);
  final_kernel<<<8, 256, 0, stream>>>(partial, out);
}

// Round 6
// 291.418 us; speedup vs baseline: 1.6273x; 1.0356x over previous
//
#include <hip/hip_runtime.h>
#include <stdint.h>

#define N_BANK 200000
#define N_PAD  201600          // 1575 steps * 128 cols
#define NQ     2048
#define DIMD   128
#define C_IN   112
#define NCB    32              // column blocks (49 or 50 128-col steps each)
#define NCE    64              // NCB * 2 wave-col halves
#define NC3    192             // NCE * 3
#define PREP_BANK_BLK 2048     // grid-stride bank-norm blocks
#define PREP_EMB_BLK  1024     // 2048 queries / 2 per block

typedef short v8s __attribute__((ext_vector_type(8)));
typedef float v4f __attribute__((ext_vector_type(4)));

typedef const __attribute__((address_space(1))) uint32_t* gp1_t;
typedef __attribute__((address_space(3))) uint32_t* lp3_t;

__device__ __forceinline__ void async16(const void* g, void* l) {
  __builtin_amdgcn_global_load_lds((gp1_t)g, (lp3_t)l, 16, 0, 0);
}

__device__ __forceinline__ unsigned short f2bf(float f) {
  uint32_t u = __float_as_uint(f);
  u += 0x7fff + ((u >> 16) & 1);   // round-to-nearest-even
  return (unsigned short)(u >> 16);
}

// running top-3 insert: 3 independent VALU ops (all read OLD state)
__device__ __forceinline__ void insert3(float& m1, float& m2, float& m3, float v) {
  m3 = __builtin_amdgcn_fmed3f(m2, m3, v);
  m2 = __builtin_amdgcn_fmed3f(m1, m2, v);
  m1 = fmaxf(m1, v);
}

// ---------------- kernel 1: fused prep = bank L2 norm + patch embedding ----
// blocks [0, 2048): grid-stride over bank rows (4 rows/wave-iter, ~25 iters)
// blocks [2048, 3072): 2 queries each (proj + L2 norm -> bf16, same swizzle)
__global__ void prep_kernel(const float* __restrict__ fm, const float* __restrict__ pw,
                            const float* __restrict__ bank,
                            unsigned short* __restrict__ embB,
                            unsigned short* __restrict__ bankB) {
  int blk = blockIdx.x;
  int tid = threadIdx.x;
  if (blk < PREP_BANK_BLK) {
    // ---- bank part: one row per wave per iteration ----
    int wv = tid >> 6, lane = tid & 63;
    uint32_t* out = (uint32_t*)bankB;     // packed 2x bf16
    int j = lane >> 2, w = lane & 3;      // 16B block, dword within
    for (int r = blk * 4 + wv; r < N_PAD; r += PREP_BANK_BLK * 4) {
      int sdw = ((j ^ (r & 15)) << 2) | w;  // swizzled dword index in row
      if (r < N_BANK) {
        float2 v = ((const float2*)bank)[r * 64 + lane];
        float s = v.x * v.x + v.y * v.y;
#pragma unroll
        for (int off = 32; off; off >>= 1) s += __shfl_xor(s, off);
        float scale = 1.f / fmaxf(sqrtf(s), 1e-12f);
        uint32_t lo = f2bf(v.x * scale);
        uint32_t hi = f2bf(v.y * scale);
        out[r * 64 + sdw] = lo | (hi << 16);
      } else {
        out[r * 64 + sdw] = 0u;
      }
    }
  } else {
    // ---- emb part: 2 queries per block (128 threads each) ----
    __shared__ float x[2][C_IN];
    __shared__ float wsum[4];
    int half = tid >> 7;                 // which query in this block
    int t = tid & 127;                   // output dim 0..127
    int q = (blk - PREP_BANK_BLK) * 2 + half; // 0..2047
    int b = q >> 8, p = q & 255;
    if (t < C_IN) x[half][t] = fm[(b * C_IN + t) * 256 + p];
    __syncthreads();
    const float* row = pw + t * C_IN;
    float dot = 0.f;
#pragma unroll
    for (int c = 0; c < C_IN; ++c) dot = fmaf(x[half][c], row[c], dot);
    float s = dot * dot;
#pragma unroll
    for (int off = 32; off; off >>= 1) s += __shfl_xor(s, off);
    int wv = tid >> 6, lane = tid & 63;
    if (lane == 0) wsum[wv] = s;
    __syncthreads();
    float ss = wsum[half * 2] + wsum[half * 2 + 1];
    float scale = 1.f / fmaxf(sqrtf(ss), 1e-12f);
    int j = t >> 3, pos = t & 7;                     // 16B block, elem within
    int sw = j ^ (q & 15);                           // bank-conflict swizzle
    embB[q * DIMD + sw * 8 + pos] = f2bf(dot * scale);
  }
}

// ---------------- kernel 2: fused sims GEMM + running top-3 -----------------
// Proven round-2 2-barrier pipeline body, re-tiled for the MEASURED 2
// blocks/CU occupancy:
//   - grid 512 = 32 column-blocks x 16 M-tiles -> exactly 2 blocks/CU,
//     zero tail (the 768-grid ran as 1.5 rounds at 2/CU: ~1.3x waste).
//   - STEP_COLS 128 (2 x 32 KB LDS buffers = 64 KB; LDS caps blocks/CU at 2
//     anyway): half the barrier/wait quanta, 256 MFMA per block-step,
//     per-step addressing overhead amortized over 2x the math.
//   - bounds(256,2): honest unified-reg cap 256, no spill risk.
//   - hoisted zero-acc constant (no per-fragment v_mov init),
//     pointer-increment staging addresses.
// 48 = 8 XCD * 4 cbs grouping for L2 locality unchanged in spirit: 32 cbs,
// 4 per XCD.
__global__ __launch_bounds__(256, 2)
void sim_top3_kernel(const unsigned short* __restrict__ embB,
                     const unsigned short* __restrict__ bankB,
                     float* __restrict__ partial) {
  int id = blockIdx.x;                 // 0..511
  int x = id & 7, j = id >> 3;         // XCD, 0..63
  int cb = x * 4 + (j >> 4);           // column block 0..31
  int mt = j & 15;                     // M tile
  // 1575 total 128-col steps: 7 cbs of 50, 25 cbs of 49
  int start = (cb < 7) ? 50 * cb : 350 + 49 * (cb - 7);
  int nsteps = (cb < 7) ? 50 : 49;
  int q0 = mt * 128;
  int tid = threadIdx.x;
  int wv = tid >> 6, lane = tid & 63;
  int wr = wv >> 1, wc = wv & 1;       // wave row/col in 2x2
  int g = lane >> 4, c0 = lane & 15;   // frag k-group / col-class

  __shared__ __align__(16) unsigned char lds[65536];   // 2 x 32 KB B buffers

  // ---- stage A tile (128 rows x 128 K, bf16, swizzled) into buf0 ----
  {
    const char* gbase = (const char*)embB + q0 * 256;
#pragma unroll
    for (int i = 0; i < 8; ++i) {
      int off = i * 4096 + tid * 16;
      async16(gbase + off, lds + off);
    }
  }
  asm volatile("s_waitcnt vmcnt(0)" ::: "memory");
  __builtin_amdgcn_sched_barrier(0);
  __builtin_amdgcn_s_barrier();

  // ---- hoist A fragments to registers, persistent for all steps ----
  v8s a[4][4];
#pragma unroll
  for (int fm = 0; fm < 4; ++fm)
#pragma unroll
    for (int k = 0; k < 4; ++k) {
      int row = wr * 64 + fm * 16 + c0;
      a[fm][k] = *(const v8s*)(lds + row * 256 + (((k * 4 + g) ^ c0) << 4));
    }
  // all waves must finish reading A before B staging overwrites the buffers
  asm volatile("s_waitcnt lgkmcnt(0)" ::: "memory");
  __builtin_amdgcn_sched_barrier(0);
  __builtin_amdgcn_s_barrier();

  float m1[16], m2[16], m3[16];
#pragma unroll
  for (int t = 0; t < 16; ++t) { m1[t] = -1e30f; m2[t] = -1e30f; m3[t] = -1e30f; }
  const v4f vzero = {0.f, 0.f, 0.f, 0.f};   // shared acc-init regs, hoisted

  const char* bbase = (const char*)bankB + (size_t)start * 32768;  // 128 cols * 256 B

  // ---- prologue: stage step 0 into buf0 (8 async16/thread = 32 KB/block) ----
#pragma unroll
  for (int i = 0; i < 8; ++i) {
    int off = i * 4096 + tid * 16;
    async16(bbase + off, lds + off);
  }

  const char* gnext = bbase + 32768;   // running pointer: step s+1 source
  for (int s = 0; s < nsteps; ++s) {
    if (s + 1 < nsteps) {
      // issue next-step stage FIRST, then wait only for the current buffer
      unsigned char* ldst = lds + ((s + 1) & 1) * 32768;
#pragma unroll
      for (int i = 0; i < 8; ++i) {
        int off = i * 4096 + tid * 16;
        async16(gnext + off, ldst + off);
      }
      gnext += 32768;
      asm volatile("s_waitcnt vmcnt(8)" ::: "memory");  // prefetch stays in flight
    } else {
      asm volatile("s_waitcnt vmcnt(0)" ::: "memory");  // epilogue: drain last buffer
    }
    __builtin_amdgcn_sched_barrier(0);
    __builtin_amdgcn_s_barrier();                       // buf[cur] ready across waves

    const unsigned char* bp = lds + (s & 1) * 32768;
#pragma unroll
    for (int fn = 0; fn < 4; ++fn) {
      v8s bf[4];
      int col = wc * 64 + fn * 16 + c0;
#pragma unroll
      for (int k = 0; k < 4; ++k)
        bf[k] = *(const v8s*)(bp + col * 256 + (((k * 4 + g) ^ c0) << 4));
#pragma unroll
      for (int fm = 0; fm < 4; ++fm) {
        v4f acc = __builtin_amdgcn_mfma_f32_16x16x32_bf16(a[fm][0], bf[0], vzero, 0, 0, 0);
#pragma unroll
        for (int k = 1; k < 4; ++k)
          acc = __builtin_amdgcn_mfma_f32_16x16x32_bf16(a[fm][k], bf[k], acc, 0, 0, 0);
#pragma unroll
        for (int j2 = 0; j2 < 4; ++j2)     // C/D: row=g*4+j2, col=c0 (within frag)
          insert3(m1[fm * 4 + j2], m2[fm * 4 + j2], m3[fm * 4 + j2], acc[j2]);
      }
    }
    // all waves done reading buf[cur] before next iteration overwrites it
    __builtin_amdgcn_s_barrier();
  }

  // ---- merge top-3 across the 16 col-class lanes (butterfly) ----
#pragma unroll
  for (int mask = 1; mask < 16; mask <<= 1) {
#pragma unroll
    for (int t = 0; t < 16; ++t) {
      float v1 = __shfl_xor(m1[t], mask);
      float v2 = __shfl_xor(m2[t], mask);
      float v3 = __shfl_xor(m3[t], mask);
      insert3(m1[t], m2[t], m3[t], v1);
      insert3(m1[t], m2[t], m3[t], v2);
      insert3(m1[t], m2[t], m3[t], v3);
    }
  }

  if (c0 == 0) {
    int ce = cb * 2 + wc;                // per wave-col half partials, 0..63
#pragma unroll
    for (int t = 0; t < 16; ++t) {
      int q = q0 + wr * 64 + (t >> 2) * 16 + g * 4 + (t & 3);
      float* dst = partial + (size_t)q * NC3 + ce * 3;   // query-major
      dst[0] = m1[t];
      dst[1] = m2[t];
      dst[2] = m3[t];
    }
  }
}

// ---------------- kernel 3: fused final = per-query merge + top-8 mean ------
// one block per image; thread q' owns query b*256+q' (scan 192 partials,
// top-3 -> distance), then in-block top-8 tree over the 256 distances.
__global__ void final_kernel(const float* __restrict__ partial, float* __restrict__ out) {
  int b = blockIdx.x;            // image
  int tid = threadIdx.x;         // patch 0..255
  int q = b * 256 + tid;
  const float* src = partial + (size_t)q * NC3;
  float m1 = -1e30f, m2 = -1e30f, m3 = -1e30f;
  for (int c = 0; c < NC3; ++c) insert3(m1, m2, m3, src[c]);
  float d1 = sqrtf(fmaxf(2.f - 2.f * m1, 0.f));
  float d2 = sqrtf(fmaxf(2.f - 2.f * m2, 0.f));
  float d3 = sqrtf(fmaxf(2.f - 2.f * m3, 0.f));
  float d = (d1 + d2 + d3) * (1.f / 3.f);

  __shared__ float vals[256];
  __shared__ float rv[256];
  __shared__ int ri[256];
  vals[tid] = d;
  __syncthreads();
  float sum = 0.f;
  for (int iter = 0; iter < 8; ++iter) {   // k = ceil(256*0.03) = 8
    rv[tid] = vals[tid]; ri[tid] = tid;
    __syncthreads();
    for (int s = 128; s > 0; s >>= 1) {
      if (tid < s && rv[tid + s] > rv[tid]) { rv[tid] = rv[tid + s]; ri[tid] = ri[tid + s]; }
      __syncthreads();
    }
    sum += rv[0];
    if (tid == 0) vals[ri[0]] = -1e30f;
    __syncthreads();
  }
  if (tid == 0) out[b] = sum * (1.f / 8.f);
}

extern "C" void kernel_launch(void* const* d_in, const int* in_sizes, int n_in,
                              void* d_out, int out_size, void* d_ws, size_t ws_size,
                              hipStream_t stream) {
  const float* fm   = (const float*)d_in[0];   // [8,112,16,16]
  const float* pw   = (const float*)d_in[1];   // [128,112]
  const float* bank = (const float*)d_in[2];   // [200000,128]
  float* out = (float*)d_out;                  // [8]

  char* ws = (char*)d_ws;
  unsigned short* bankB = (unsigned short*)ws;                       // 51,609,600 B
  unsigned short* embB  = (unsigned short*)(ws + 51609600);          //    524,288 B
  float* partial        = (float*)(ws + 51609600 + 524288);          //  1,572,864 B

  prep_kernel<<<PREP_BANK_BLK + PREP_EMB_BLK, 256, 0, stream>>>(fm, pw, bank, embB, bankB);
  sim_top3_kernel<<<512, 256, 0, stream>>>(embB, bankB, partial);
  final_kernel<<<8, 256, 0, stream>>>(partial, out);
}